// Round 8
// baseline (37817.233 us; speedup 1.0000x reference)
//
#include <hip/hip_runtime.h>
#include <cstdint>
#include <cstddef>

#define TT 512

// ---- ws layout (float offsets) ----
#define O_HBUF 0                            // [3][2][64][512] h ping-pong (linear)
#define O_CBUF (3*2*64*512)                 // [3][64][512]    c state
#define WS_STATE (O_CBUF + 3*64*512)        // 294912 floats = 1.18 MB
#define O_CW0  WS_STATE                     // [2048 cols][512]  U0^T
#define O_CW1  (O_CW0 + 2048*512)           // [2048 cols][1024] [W1;U1]^T
#define O_CW2  (O_CW1 + 2048*1024)          // [2048 cols][1024] [W2;U2]^T
#define O_W0T  (O_CW2 + 2048*1024)          // [2048 cols][8]    W0^T
#define WS_FAST (O_W0T + 2048*8)            // 5554176 floats = 22.2 MB

// One LSTM layer phase for one time-step. Block owns hidden unit u=bid
// => gate cols col(g) = 512*g + u. Wave w handles k-quarter [w*K/4,(w+1)*K/4).
// h read directly from global (L1/L2-served); weights via wave-uniform s_loads.
// Accuracy: 32-term f32 fma chains, f64 accumulation across 32-k groups.
__device__ __forceinline__ void lstm_phase(
    int l0flag, int Ktot, const float* __restrict__ CW, int Kt,
    const float* __restrict__ srcA, const float* __restrict__ srcB,
    const float* __restrict__ bias, float* __restrict__ hdst, float* __restrict__ cslab,
    const int* __restrict__ tokens, const float* __restrict__ emb,
    const float* __restrict__ W0T, int t,
    double* dz, int u, int tid)
{
  const int lane = tid & 63;                                  // batch row
  const int w = __builtin_amdgcn_readfirstlane(tid >> 6);     // wave -> SGPR
  const int Kq = Ktot >> 2;
  const int k0 = w * Kq, k1 = k0 + Kq;
  const float* hsrc = (Ktot == 512 || w < 2) ? srcA : srcB;   // wave-uniform
  const int kof = (Ktot == 512 || w < 2) ? 0 : 512;
  const float* hrow = hsrc + (size_t)lane * 512 - kof;
  const float* wg0 = CW + (size_t)(0 * 512 + u) * Kt;
  const float* wg1 = CW + (size_t)(1 * 512 + u) * Kt;
  const float* wg2 = CW + (size_t)(2 * 512 + u) * Kt;
  const float* wg3 = CW + (size_t)(3 * 512 + u) * Kt;
  double d[4] = {0.0, 0.0, 0.0, 0.0};

  for (int kb = k0; kb < k1; kb += 32) {
    float s0 = 0.f, s1 = 0.f, s2 = 0.f, s3 = 0.f;
#pragma unroll
    for (int q = 0; q < 8; ++q) {
      const int k = kb + q * 4;
      const float4 xv = *(const float4*)&hrow[k];             // per-lane global
      const float4 a0 = *(const float4*)&wg0[k];              // uniform -> s_load
      const float4 a1 = *(const float4*)&wg1[k];
      const float4 a2 = *(const float4*)&wg2[k];
      const float4 a3 = *(const float4*)&wg3[k];
      s0 = fmaf(xv.w, a0.w, fmaf(xv.z, a0.z, fmaf(xv.y, a0.y, fmaf(xv.x, a0.x, s0))));
      s1 = fmaf(xv.w, a1.w, fmaf(xv.z, a1.z, fmaf(xv.y, a1.y, fmaf(xv.x, a1.x, s1))));
      s2 = fmaf(xv.w, a2.w, fmaf(xv.z, a2.z, fmaf(xv.y, a2.y, fmaf(xv.x, a2.x, s2))));
      s3 = fmaf(xv.w, a3.w, fmaf(xv.z, a3.z, fmaf(xv.y, a3.y, fmaf(xv.x, a3.x, s3))));
    }
    d[0] += (double)s0; d[1] += (double)s1;                   // per-32k f64 flush
    d[2] += (double)s2; d[3] += (double)s3;
  }

  if (l0flag && w == 0) {                  // embedding K=8 part (once, wave 0)
    const int tok = tokens[lane * TT + t];
    const float4 e0 = *(const float4*)&emb[tok * 8];
    const float4 e1 = *(const float4*)&emb[tok * 8 + 4];
#pragma unroll
    for (int g = 0; g < 4; ++g) {
      const float4 a0 = *(const float4*)&W0T[((g << 9) + u) * 8];
      const float4 a1 = *(const float4*)&W0T[((g << 9) + u) * 8 + 4];
      float sa = e0.x * a0.x + e0.y * a0.y + e0.z * a0.z + e0.w * a0.w
               + e1.x * a1.x + e1.y * a1.y + e1.z * a1.z + e1.w * a1.w;
      d[g] += (double)sa;
    }
  }

#pragma unroll
  for (int g = 0; g < 4; ++g) dz[tid * 4 + g] = d[g];
  __syncthreads();

  if (tid < 64) {
    const int m = tid;
    float zf[4];
#pragma unroll
    for (int g = 0; g < 4; ++g) {
      const double zs = dz[(0 * 64 + m) * 4 + g] + dz[(1 * 64 + m) * 4 + g]
                      + dz[(2 * 64 + m) * 4 + g] + dz[(3 * 64 + m) * 4 + g]
                      + (double)bias[(g << 9) + u];
      zf[g] = (float)zs;
    }
    const float iv = 1.f / (1.f + expf(-zf[0]));
    const float fv = 1.f / (1.f + expf(-zf[1]));
    const float gv = tanhf(zf[2]);
    const float ov = 1.f / (1.f + expf(-zf[3]));
    float* cp = cslab + m * 512 + u;
    const float cn = fv * cp[0] + iv * gv;
    cp[0] = cn;
    hdst[m * 512 + u] = ov * tanhf(cn);    // linear storage
  }
  __syncthreads();                         // dz safe for next phase
}

__global__ void __launch_bounds__(256)
rnn_prep(float* __restrict__ ws,
         const float* __restrict__ W0, const float* __restrict__ U0,
         const float* __restrict__ W1, const float* __restrict__ U1,
         const float* __restrict__ W2, const float* __restrict__ U2)
{
  __shared__ float tile[64 * 65];
  const int tid = (int)threadIdx.x;
  const int bid = (int)blockIdx.x;
  const int gtid = bid * 256 + tid;
  for (int i = gtid; i < WS_STATE; i += 512 * 256) ws[i] = 0.f;

  float* CW0 = ws + O_CW0;
  float* CW1 = ws + O_CW1;
  float* CW2 = ws + O_CW2;
  float* W0T = ws + O_W0T;
  if (gtid < 2048) {
#pragma unroll
    for (int e = 0; e < 8; ++e) W0T[gtid * 8 + e] = W0[(size_t)e * 2048 + gtid];
  }
  // LDS-tiled transpose: 1280 [64k x 64col] tiles over 512 blocks
  for (int tl = bid; tl < 1280; tl += 512) {
    const int kt = tl >> 5, ct = tl & 31;
    const int col0 = ct * 64;
    const float* src; float* dst; int K, k0, sk0;
    if (kt < 8)       { dst = CW0; K = 512;  k0 = kt * 64;        src = U0; sk0 = k0; }
    else if (kt < 24) { const int j = kt - 8;  dst = CW1; K = 1024; k0 = j * 64;
                        src = (j < 8) ? W1 : U1; sk0 = (j < 8) ? k0 : k0 - 512; }
    else              { const int j = kt - 24; dst = CW2; K = 1024; k0 = j * 64;
                        src = (j < 8) ? W2 : U2; sk0 = (j < 8) ? k0 : k0 - 512; }
    __syncthreads();                       // tile reusable
    const int c = tid & 63, r4 = tid >> 6;
    for (int r0 = 0; r0 < 64; r0 += 4)     // coalesced row reads
      tile[(r0 + r4) * 65 + c] = src[(size_t)(sk0 + r0 + r4) * 2048 + col0 + c];
    __syncthreads();
    const int w = tid >> 6, lane = tid & 63;
    for (int ci = w; ci < 64; ci += 4)     // coalesced col writes (64 consecutive k)
      dst[(size_t)(col0 + ci) * K + k0 + lane] = tile[lane * 65 + ci];
  }
}

__global__ void __launch_bounds__(256, 3)
rnn_step(const int* __restrict__ tokens, const float* __restrict__ emb,
         const float* __restrict__ b0, const float* __restrict__ b1,
         const float* __restrict__ b2,
         const float* __restrict__ Wd, const float* __restrict__ bd,
         float* __restrict__ out, float* __restrict__ ws, int s)
{
  __shared__ double dz[1024];                  // 8 KiB partials
  __shared__ float red[256];                   // 1 KiB softmax reduce
  const int tid = (int)threadIdx.x;
  const int bid = (int)blockIdx.x;             // = hidden unit u
  float* hb = ws + O_HBUF;
  float* cb = ws + O_CBUF;
  const float* CW0 = ws + O_CW0;
  const float* CW1 = ws + O_CW1;
  const float* CW2 = ws + O_CW2;
  const float* W0T = ws + O_W0T;
  const int po = (s + 1) & 1;                  // parity of prev-superstep outputs
  const int pw = s & 1;                        // parity written this superstep
  float* h0po = hb + (size_t)(0 * 2 + po) * 32768;
  float* h1po = hb + (size_t)(1 * 2 + po) * 32768;
  float* h2po = hb + (size_t)(2 * 2 + po) * 32768;
  float* h0pw = hb + (size_t)(0 * 2 + pw) * 32768;
  float* h1pw = hb + (size_t)(1 * 2 + pw) * 32768;
  float* h2pw = hb + (size_t)(2 * 2 + pw) * 32768;

  if (s < 512)                                 // L0: t=s (K=512 recurrent + emb K=8)
    lstm_phase(1, 512, CW0, 512, h0po, h0po, b0, h0pw, cb + 0 * 32768,
               tokens, emb, W0T, s, dz, bid, tid);
  if (s >= 1 && s < 513)                       // L1: t=s-1
    lstm_phase(0, 1024, CW1, 1024, h0po, h1po, b1, h1pw, cb + 1 * 32768,
               nullptr, nullptr, nullptr, 0, dz, bid, tid);
  if (s >= 2 && s < 514)                       // L2: t=s-2
    lstm_phase(0, 1024, CW2, 1024, h1po, h2po, b2, h2pw, cb + 2 * 32768,
               nullptr, nullptr, nullptr, 0, dz, bid, tid);

  if (s >= 3 && bid < 64) {                    // FIN: logits+softmax for t=s-3 (row bid)
    const int r = bid;
    const float* h2row = h2po + (size_t)r * 512;   // linear now
    const int col = tid & 127, kh = tid >> 7;
    const float* frb = h2row + kh * 256;           // uniform -> s_load
    const float* wdb = Wd + (size_t)kh * 256 * 128 + col;
    double a = 0.0;
#pragma unroll 4
    for (int j = 0; j < 256; j += 4) {
      float sa = frb[j] * wdb[(size_t)j * 128];
      sa = fmaf(frb[j + 1], wdb[(size_t)(j + 1) * 128], sa);
      sa = fmaf(frb[j + 2], wdb[(size_t)(j + 2) * 128], sa);
      sa = fmaf(frb[j + 3], wdb[(size_t)(j + 3) * 128], sa);
      a += (double)sa;
    }
    dz[tid] = a;
    __syncthreads();
    float xlg = -3.0e38f;
    if (tid < 128) xlg = (float)(dz[tid] + dz[128 + tid] + (double)bd[tid]);
    red[tid] = xlg;                       __syncthreads();
    if (tid < 128) red[tid] = fmaxf(red[tid], red[tid + 128]); __syncthreads();
    if (tid < 64)  red[tid] = fmaxf(red[tid], red[tid + 64]);  __syncthreads();
    if (tid < 32)  red[tid] = fmaxf(red[tid], red[tid + 32]);  __syncthreads();
    if (tid < 16)  red[tid] = fmaxf(red[tid], red[tid + 16]);  __syncthreads();
    if (tid < 8)   red[tid] = fmaxf(red[tid], red[tid + 8]);   __syncthreads();
    if (tid < 4)   red[tid] = fmaxf(red[tid], red[tid + 4]);   __syncthreads();
    if (tid < 2)   red[tid] = fmaxf(red[tid], red[tid + 2]);   __syncthreads();
    if (tid < 1)   red[tid] = fmaxf(red[tid], red[tid + 1]);   __syncthreads();
    const float mx = red[0];              __syncthreads();
    const float ex = (tid < 128) ? expf(xlg - mx) : 0.f;
    red[tid] = ex;                        __syncthreads();
    if (tid < 128) red[tid] += red[tid + 128]; __syncthreads();
    if (tid < 64)  red[tid] += red[tid + 64];  __syncthreads();
    if (tid < 32)  red[tid] += red[tid + 32];  __syncthreads();
    if (tid < 16)  red[tid] += red[tid + 16];  __syncthreads();
    if (tid < 8)   red[tid] += red[tid + 8];   __syncthreads();
    if (tid < 4)   red[tid] += red[tid + 4];   __syncthreads();
    if (tid < 2)   red[tid] += red[tid + 2];   __syncthreads();
    if (tid < 1)   red[tid] += red[tid + 1];   __syncthreads();
    const float inv = 1.f / red[0];
    if (tid < 128) out[((size_t)r * 512 + (s - 3)) * 128 + tid] = ex * inv;
  }
}

extern "C" void kernel_launch(void* const* d_in, const int* in_sizes, int n_in,
                              void* d_out, int out_size, void* d_ws, size_t ws_size,
                              hipStream_t stream) {
  (void)in_sizes; (void)n_in; (void)out_size;
  if (ws_size < (size_t)WS_FAST * 4) return;   // needs 22.2 MB (proven available)
  const int*   tokens = (const int*)d_in[0];
  const float* emb = (const float*)d_in[1];
  const float* W0 = (const float*)d_in[2];
  const float* U0 = (const float*)d_in[3];
  const float* b0 = (const float*)d_in[4];
  const float* W1 = (const float*)d_in[5];
  const float* U1 = (const float*)d_in[6];
  const float* b1 = (const float*)d_in[7];
  const float* W2 = (const float*)d_in[8];
  const float* U2 = (const float*)d_in[9];
  const float* b2 = (const float*)d_in[10];
  const float* Wd = (const float*)d_in[11];
  const float* bd = (const float*)d_in[12];
  float* out = (float*)d_out;
  float* ws  = (float*)d_ws;

  hipLaunchKernelGGL(rnn_prep, dim3(512), dim3(256), 0, stream,
                     ws, W0, U0, W1, U1, W2, U2);
  for (int s = 0; s < 515; ++s)
    hipLaunchKernelGGL(rnn_step, dim3(512), dim3(256), 0, stream,
                       tokens, emb, b0, b1, b2, Wd, bd, out, ws, s);
}

// Round 9
// 25927.310 us; speedup vs baseline: 1.4586x; 1.4586x over previous
//
#include <hip/hip_runtime.h>
#include <cstdint>
#include <cstddef>

#define TT 512

// ---- ws layout (float offsets) ----  total 5554176 floats = 22.2 MB (proven OK)
#define O_HT   0                            // [3 layer][2 parity][512 k][64 m]  h^T
#define O_CT   (3*2*512*64)                 // [3 layer][512 u][64 m]            c^T
#define WS_STATE (O_CT + 3*512*64)          // 294912
#define O_CWP0 WS_STATE                     // [256 p][512 k][8 j]   U0 packed
#define O_CWP1 (O_CWP0 + 256*512*8)         // [256 p][1024 k][8 j]  [W1;U1] packed
#define O_CWP2 (O_CWP1 + 256*1024*8)        // [256 p][1024 k][8 j]  [W2;U2] packed
#define O_W0P  (O_CWP2 + 256*1024*8)        // [256 p][8 e][8 j]     W0 packed
#define WS_ALL (O_W0P + 256*64)             // 5554176

// One LSTM layer phase. Block owns unit pair p => 8 gate cols j=g*2+uu,
// col(j) = 512*g + 2p + uu. 8 waves k-split K into eighths.
// h^T reads coalesced (lane=batch row m); weights via uniform 32B s_loads.
// Accuracy: 32-term f32 fma chains, f64 accumulation across 32-k groups.
__device__ __forceinline__ void lstm_phase(
    int l0flag, int Ktot, const float* __restrict__ CWP, const float* __restrict__ W0P,
    const float* __restrict__ belowT, const float* __restrict__ ownT,
    const float* __restrict__ bias, float* __restrict__ hdstT, float* __restrict__ cslab,
    const int* __restrict__ tokens, const float* __restrict__ emb, int t,
    double* dz, int p, int tid)
{
  const int lane = tid & 63;                                  // batch row m
  const int w = __builtin_amdgcn_readfirstlane(tid >> 6);     // wave 0..7 -> SGPR
  const int Kq = Ktot >> 3;
  const int k0 = w * Kq;
  const float* hsrc = (Ktot == 512 || w < 4) ? belowT : ownT; // wave-uniform
  const int kbase = (Ktot == 512 || w < 4) ? k0 : k0 - 512;
  const float* wp = CWP + ((size_t)p * Ktot + k0) * 8;        // sequential stream
  double d[8] = {0.0, 0.0, 0.0, 0.0, 0.0, 0.0, 0.0, 0.0};

  for (int kb = 0; kb < Kq; kb += 32) {
    float s8[8] = {0.f, 0.f, 0.f, 0.f, 0.f, 0.f, 0.f, 0.f};
#pragma unroll
    for (int kk = 0; kk < 32; ++kk) {
      const float xk = hsrc[(size_t)(kbase + kb + kk) * 64 + lane];  // coalesced 256B
      const float4 wa = *(const float4*)&wp[(kb + kk) * 8];          // uniform s_load
      const float4 wb = *(const float4*)&wp[(kb + kk) * 8 + 4];
      s8[0] = fmaf(xk, wa.x, s8[0]); s8[1] = fmaf(xk, wa.y, s8[1]);
      s8[2] = fmaf(xk, wa.z, s8[2]); s8[3] = fmaf(xk, wa.w, s8[3]);
      s8[4] = fmaf(xk, wb.x, s8[4]); s8[5] = fmaf(xk, wb.y, s8[5]);
      s8[6] = fmaf(xk, wb.z, s8[6]); s8[7] = fmaf(xk, wb.w, s8[7]);
    }
#pragma unroll
    for (int j = 0; j < 8; ++j) d[j] += (double)s8[j];        // per-32k f64 flush
  }

  if (l0flag && w == 0) {                  // embedding K=8 part (once, wave 0)
    const int tok = tokens[lane * TT + t];
    float s8[8] = {0.f, 0.f, 0.f, 0.f, 0.f, 0.f, 0.f, 0.f};
#pragma unroll
    for (int e = 0; e < 8; ++e) {
      const float xe = emb[tok * 8 + e];
      const float4 wa = *(const float4*)&W0P[p * 64 + e * 8];
      const float4 wb = *(const float4*)&W0P[p * 64 + e * 8 + 4];
      s8[0] = fmaf(xe, wa.x, s8[0]); s8[1] = fmaf(xe, wa.y, s8[1]);
      s8[2] = fmaf(xe, wa.z, s8[2]); s8[3] = fmaf(xe, wa.w, s8[3]);
      s8[4] = fmaf(xe, wb.x, s8[4]); s8[5] = fmaf(xe, wb.y, s8[5]);
      s8[6] = fmaf(xe, wb.z, s8[6]); s8[7] = fmaf(xe, wb.w, s8[7]);
    }
#pragma unroll
    for (int j = 0; j < 8; ++j) d[j] += (double)s8[j];
  }

#pragma unroll
  for (int j = 0; j < 8; ++j) dz[tid * 8 + j] = d[j];
  __syncthreads();

  if (tid < 128) {
    const int m = tid & 63, uu = tid >> 6;
    const int u = 2 * p + uu;
    float zf[4];
#pragma unroll
    for (int g = 0; g < 4; ++g) {
      double zs = (double)bias[(g << 9) + u];
#pragma unroll
      for (int w8 = 0; w8 < 8; ++w8) zs += dz[(w8 * 64 + m) * 8 + g * 2 + uu];
      zf[g] = (float)zs;
    }
    const float iv = 1.f / (1.f + expf(-zf[0]));
    const float fv = 1.f / (1.f + expf(-zf[1]));
    const float gv = tanhf(zf[2]);
    const float ov = 1.f / (1.f + expf(-zf[3]));
    float* cp = cslab + u * 64 + m;              // c^T: coalesced over m
    const float cn = fv * cp[0] + iv * gv;
    cp[0] = cn;
    hdstT[u * 64 + m] = ov * tanhf(cn);          // h^T: coalesced over m
  }
  __syncthreads();                               // dz safe for next phase
}

__global__ void __launch_bounds__(256)
rnn_prep(float* __restrict__ ws,
         const float* __restrict__ W0, const float* __restrict__ U0,
         const float* __restrict__ W1, const float* __restrict__ U1,
         const float* __restrict__ W2, const float* __restrict__ U2)
{
  const int tid = (int)threadIdx.x;
  const int bid = (int)blockIdx.x;
  const int gtid = bid * 256 + tid;
  for (int i = gtid; i < WS_STATE; i += 768 * 256) ws[i] = 0.f;

  float* CWP0 = ws + O_CWP0;
  float* CWP1 = ws + O_CWP1;
  float* CWP2 = ws + O_CWP2;
  float* W0P  = ws + O_W0P;
  if (bid < 256) {
    const int p = bid;
    for (int k = tid; k < 512; k += 256)
#pragma unroll
      for (int j = 0; j < 8; ++j) {
        const int col = ((j >> 1) << 9) + 2 * p + (j & 1);
        CWP0[((size_t)p * 512 + k) * 8 + j] = U0[(size_t)k * 2048 + col];
      }
    if (tid < 64) {
      const int e = tid >> 3, j = tid & 7;
      const int col = ((j >> 1) << 9) + 2 * p + (j & 1);
      W0P[p * 64 + e * 8 + j] = W0[(size_t)e * 2048 + col];
    }
  } else if (bid < 512) {
    const int p = bid - 256;
    for (int k = tid; k < 1024; k += 256) {
      const float* src = (k < 512) ? &W1[(size_t)k * 2048] : &U1[(size_t)(k - 512) * 2048];
#pragma unroll
      for (int j = 0; j < 8; ++j) {
        const int col = ((j >> 1) << 9) + 2 * p + (j & 1);
        CWP1[((size_t)p * 1024 + k) * 8 + j] = src[col];
      }
    }
  } else {
    const int p = bid - 512;
    for (int k = tid; k < 1024; k += 256) {
      const float* src = (k < 512) ? &W2[(size_t)k * 2048] : &U2[(size_t)(k - 512) * 2048];
#pragma unroll
      for (int j = 0; j < 8; ++j) {
        const int col = ((j >> 1) << 9) + 2 * p + (j & 1);
        CWP2[((size_t)p * 1024 + k) * 8 + j] = src[col];
      }
    }
  }
}

__global__ void __launch_bounds__(512, 4)
rnn_step(const int* __restrict__ tokens, const float* __restrict__ emb,
         const float* __restrict__ b0, const float* __restrict__ b1,
         const float* __restrict__ b2,
         const float* __restrict__ Wd, const float* __restrict__ bd,
         float* __restrict__ out, float* __restrict__ ws, int s)
{
  __shared__ double dz[4096];                  // 32 KiB partials
  __shared__ float red[512];                   // 2 KiB softmax reduce
  const int tid = (int)threadIdx.x;
  const int bid = (int)blockIdx.x;
  float* ht = ws + O_HT;
  float* ct = ws + O_CT;
  const int po = (s + 1) & 1;                  // parity of prev-superstep outputs
  const int pw = s & 1;                        // parity written this superstep
  float* h0po = ht + (size_t)(0 * 2 + po) * 32768;
  float* h1po = ht + (size_t)(1 * 2 + po) * 32768;
  float* h2po = ht + (size_t)(2 * 2 + po) * 32768;
  float* h0pw = ht + (size_t)(0 * 2 + pw) * 32768;
  float* h1pw = ht + (size_t)(1 * 2 + pw) * 32768;
  float* h2pw = ht + (size_t)(2 * 2 + pw) * 32768;

  if (bid < 256) {                             // LSTM path: unit pair p = bid
    const int p = bid;
    const float* CWP0 = ws + O_CWP0;
    const float* CWP1 = ws + O_CWP1;
    const float* CWP2 = ws + O_CWP2;
    const float* W0P  = ws + O_W0P;
    if (s < 512)                               // L0: t=s (K=512 recurrent + emb K=8)
      lstm_phase(1, 512, CWP0, W0P, h0po, h0po, b0, h0pw, ct + 0 * 32768,
                 tokens, emb, s, dz, p, tid);
    if (s >= 1 && s < 513)                     // L1: t=s-1
      lstm_phase(0, 1024, CWP1, nullptr, h0po, h1po, b1, h1pw, ct + 1 * 32768,
                 nullptr, nullptr, 0, dz, p, tid);
    if (s >= 2 && s < 514)                     // L2: t=s-2
      lstm_phase(0, 1024, CWP2, nullptr, h1po, h2po, b2, h2pw, ct + 2 * 32768,
                 nullptr, nullptr, 0, dz, p, tid);
  } else if (s >= 3) {                         // FIN: logits+softmax, t=s-3, row r
    const int r = bid - 256;
    const int col = tid & 127, kq = tid >> 7;  // kq wave-uniform (wave>>1)
    double acc = 0.0;
    for (int kb = 0; kb < 128; kb += 32) {
      float sa = 0.f;
#pragma unroll
      for (int kk = 0; kk < 32; ++kk) {
        const int k = kq * 128 + kb + kk;
        sa = fmaf(h2po[(size_t)k * 64 + r],          // uniform -> s_load broadcast
                  Wd[(size_t)k * 128 + col], sa);    // coalesced
      }
      acc += (double)sa;
    }
    dz[tid] = acc;
    __syncthreads();
    float xlg = -3.0e38f;
    if (tid < 128)
      xlg = (float)(dz[tid] + dz[tid + 128] + dz[tid + 256] + dz[tid + 384]
                    + (double)bd[col]);
    red[tid] = xlg;                       __syncthreads();
    if (tid < 256) red[tid] = fmaxf(red[tid], red[tid + 256]); __syncthreads();
    if (tid < 128) red[tid] = fmaxf(red[tid], red[tid + 128]); __syncthreads();
    if (tid < 64)  red[tid] = fmaxf(red[tid], red[tid + 64]);  __syncthreads();
    if (tid < 32)  red[tid] = fmaxf(red[tid], red[tid + 32]);  __syncthreads();
    if (tid < 16)  red[tid] = fmaxf(red[tid], red[tid + 16]);  __syncthreads();
    if (tid < 8)   red[tid] = fmaxf(red[tid], red[tid + 8]);   __syncthreads();
    if (tid < 4)   red[tid] = fmaxf(red[tid], red[tid + 4]);   __syncthreads();
    if (tid < 2)   red[tid] = fmaxf(red[tid], red[tid + 2]);   __syncthreads();
    if (tid < 1)   red[tid] = fmaxf(red[tid], red[tid + 1]);   __syncthreads();
    const float mx = red[0];              __syncthreads();
    const float ex = (tid < 128) ? expf(xlg - mx) : 0.f;
    red[tid] = ex;                        __syncthreads();
    if (tid < 256) red[tid] += red[tid + 256]; __syncthreads();
    if (tid < 128) red[tid] += red[tid + 128]; __syncthreads();
    if (tid < 64)  red[tid] += red[tid + 64];  __syncthreads();
    if (tid < 32)  red[tid] += red[tid + 32];  __syncthreads();
    if (tid < 16)  red[tid] += red[tid + 16];  __syncthreads();
    if (tid < 8)   red[tid] += red[tid + 8];   __syncthreads();
    if (tid < 4)   red[tid] += red[tid + 4];   __syncthreads();
    if (tid < 2)   red[tid] += red[tid + 2];   __syncthreads();
    if (tid < 1)   red[tid] += red[tid + 1];   __syncthreads();
    const float inv = 1.f / red[0];
    if (tid < 128) out[((size_t)r * 512 + (s - 3)) * 128 + tid] = ex * inv;
  }
}

extern "C" void kernel_launch(void* const* d_in, const int* in_sizes, int n_in,
                              void* d_out, int out_size, void* d_ws, size_t ws_size,
                              hipStream_t stream) {
  (void)in_sizes; (void)n_in; (void)out_size;
  if (ws_size < (size_t)WS_ALL * 4) return;    // 22.2 MB, proven available
  const int*   tokens = (const int*)d_in[0];
  const float* emb = (const float*)d_in[1];
  const float* W0 = (const float*)d_in[2];
  const float* U0 = (const float*)d_in[3];
  const float* b0 = (const float*)d_in[4];
  const float* W1 = (const float*)d_in[5];
  const float* U1 = (const float*)d_in[6];
  const float* b1 = (const float*)d_in[7];
  const float* W2 = (const float*)d_in[8];
  const float* U2 = (const float*)d_in[9];
  const float* b2 = (const float*)d_in[10];
  const float* Wd = (const float*)d_in[11];
  const float* bd = (const float*)d_in[12];
  float* out = (float*)d_out;
  float* ws  = (float*)d_ws;

  hipLaunchKernelGGL(rnn_prep, dim3(768), dim3(256), 0, stream,
                     ws, W0, U0, W1, U1, W2, U2);
  for (int s = 0; s < 515; ++s)
    hipLaunchKernelGGL(rnn_step, dim3(320), dim3(512), 0, stream,
                       tokens, emb, b0, b1, b2, Wd, bd, out, ws, s);
}